// Round 4
// baseline (402.978 us; speedup 1.0000x reference)
//
#include <hip/hip_runtime.h>
#include <hip/hip_bf16.h>
#include <stdint.h>

#define B_  256
#define L_  256
#define S_  253
#define SP_ 256   // padded S
#define D_  768
#define H_  128

typedef __bf16 bf16x8 __attribute__((ext_vector_type(8)));
typedef float  f32x4  __attribute__((ext_vector_type(4)));

__device__ __forceinline__ ushort f2bf(float f) {
  union { float f; uint32_t u; } v; v.f = f;
  uint32_t r = v.u + 0x7FFFu + ((v.u >> 16) & 1u);  // RNE
  return (ushort)(r >> 16);
}

__device__ __forceinline__ uint32_t pk2(float a, float b) {
  return (uint32_t)f2bf(a) | ((uint32_t)f2bf(b) << 16);
}

__device__ __forceinline__ void gload16(const void* g, void* l) {
  __builtin_amdgcn_global_load_lds((const __attribute__((address_space(1))) void*)g,
                                   (__attribute__((address_space(3))) void*)l,
                                   16, 0, 0);
}

// ---------------- k0: Mt[i][j] = scale * sum_t WK[i,t] * WQ[j,t] (bf16) -----
__global__ __launch_bounds__(256) void k_mt(const float* __restrict__ WK,
                                            const float* __restrict__ WQ,
                                            ushort* __restrict__ Mt) {
  const float scale = 0.03608439182435161f;  // 1/sqrt(768)
  int bid = blockIdx.x;
  int i0 = (bid / 3) * 4;
  int j  = (bid % 3) * 256 + threadIdx.x;
  const float4* wq  = (const float4*)(WQ + (size_t)j * D_);
  const float4* wk0 = (const float4*)(WK + (size_t)(i0 + 0) * D_);
  const float4* wk1 = (const float4*)(WK + (size_t)(i0 + 1) * D_);
  const float4* wk2 = (const float4*)(WK + (size_t)(i0 + 2) * D_);
  const float4* wk3 = (const float4*)(WK + (size_t)(i0 + 3) * D_);
  float a0 = 0.f, a1 = 0.f, a2 = 0.f, a3 = 0.f;
#pragma unroll 4
  for (int t = 0; t < D_ / 4; ++t) {
    float4 q = wq[t];
    float4 k0 = wk0[t], k1 = wk1[t], k2 = wk2[t], k3 = wk3[t];
    a0 += q.x * k0.x + q.y * k0.y + q.z * k0.z + q.w * k0.w;
    a1 += q.x * k1.x + q.y * k1.y + q.z * k1.z + q.w * k1.w;
    a2 += q.x * k2.x + q.y * k2.y + q.z * k2.z + q.w * k2.w;
    a3 += q.x * k3.x + q.y * k3.y + q.z * k3.z + q.w * k3.w;
  }
  Mt[(size_t)(i0 + 0) * D_ + j] = f2bf(a0 * scale);
  Mt[(size_t)(i0 + 1) * D_ + j] = f2bf(a1 * scale);
  Mt[(size_t)(i0 + 2) * D_ + j] = f2bf(a2 * scale);
  Mt[(size_t)(i0 + 3) * D_ + j] = f2bf(a3 * scale);
}

// ---------------- k1: cand -> bf16 (padded), w[b,s] = mask * (cand . WV) ----
__global__ __launch_bounds__(256) void k_cand(const float* __restrict__ cand,
                                              const int* __restrict__ cand_mask,
                                              const float* __restrict__ WV,
                                              ushort* __restrict__ candb,
                                              float* __restrict__ wbuf) {
  int r = blockIdx.x * 4 + (threadIdx.x >> 6);  // padded row id, one wave per row
  int l = threadIdx.x & 63;
  int b = r >> 8, s = r & 255;
  float acc = 0.f;
  ushort* dst = candb + (size_t)r * D_;
  if (s < S_) {
    const float4* src = (const float4*)(cand + ((size_t)b * S_ + s) * D_);
    const float4* wv4 = (const float4*)WV;
#pragma unroll
    for (int i = 0; i < 3; ++i) {
      int d4 = i * 64 + l;
      float4 c = src[d4];
      float4 v = wv4[d4];
      acc += c.x * v.x + c.y * v.y + c.z * v.z + c.w * v.w;
      ushort4 o;
      o.x = f2bf(c.x); o.y = f2bf(c.y); o.z = f2bf(c.z); o.w = f2bf(c.w);
      *(ushort4*)(dst + d4 * 4) = o;
    }
  } else {
    ushort4 z = {0, 0, 0, 0};
#pragma unroll
    for (int i = 0; i < 3; ++i) *(ushort4*)(dst + (i * 64 + l) * 4) = z;
  }
#pragma unroll
  for (int off = 32; off > 0; off >>= 1) acc += __shfl_down(acc, off, 64);
  if (l == 0) {
    float wv = 0.f;
    if (s < S_ && cand_mask[(size_t)b * S_ + s] != 0) wv = acc;
    wbuf[r] = wv;
  }
}

// ---------------- k2: qm[r][c] = sum_k ctx[r][k] * Mt[c][k]  (bf16 out) -----
// 128x128 tile, BK=64 as two [rows][32] bf16 panels. A: reg-staged f32->bf16
// (no ctxb pass). B: gload_lds(16B) with pre-swizzled source. XOR slot
// swizzle (lane-constant) balances banks on fragment ds_read_b128.
__global__ __launch_bounds__(256) void k_qm(const float* __restrict__ ctx,
                                            const ushort* __restrict__ Mt,
                                            ushort* __restrict__ qm) {
  __shared__ __align__(16) ushort As[2][128 * 32 + 8];  // +8: de-phase panel banks
  __shared__ __align__(16) ushort Bs[2][128 * 32 + 8];
  int bid0 = blockIdx.x;              // 0..3071
  int xcd = bid0 & 7;
  int idx = bid0 >> 3;                // 0..383
  int bm = xcd * 64 + idx / 6;        // 0..511 (bijective)
  int bn = idx % 6;
  int row0 = bm * 128, col0 = bn * 128;
  int tid = threadIdx.x;
  int w = tid >> 6, l = tid & 63;
  int wr = w >> 1, wc = w & 1;
  int rd_off  = (((l >> 4) ^ ((l >> 2) & 3)) * 8);  // swizzled frag-read slot
  int src_off = (((l & 3) ^ ((l >> 4) & 3)) * 8);   // pre-swizzled gload src col

  // A staging: thread -> (row ar, panel ah); 32 f32 -> 32 bf16 per K-step
  int ar  = tid >> 1;
  int ah  = tid & 1;
  int axr = (ar >> 2) & 3;            // row-dependent slot swizzle for A writes
  const float* actx = ctx + (size_t)(row0 + ar) * D_ + ah * 32;
  ushort* a_base = &As[ah][ar * 32];

  f32x4 acc[4][4];
#pragma unroll
  for (int m = 0; m < 4; ++m)
#pragma unroll
    for (int n = 0; n < 4; ++n) acc[m][n] = (f32x4){0.f, 0.f, 0.f, 0.f};

  for (int kt = 0; kt < D_; kt += 64) {
    if (kt) __syncthreads();
    // B: async global->LDS, 2 panels x 2 groups per wave
#pragma unroll
    for (int h = 0; h < 2; ++h)
#pragma unroll
      for (int g = 0; g < 2; ++g) {
        int grp = w * 2 + g;
        const ushort* bsrc = Mt + (size_t)(col0 + grp * 16 + (l >> 2)) * D_
                                + kt + h * 32 + src_off;
        gload16(bsrc, (char*)Bs[h] + grp * 1024);
      }
    // A: 8 float4 loads -> 32 bf16 -> 4 swizzled ds_write_b128
    {
      const float4* ap = (const float4*)(actx + kt);
      float4 f0 = ap[0], f1 = ap[1], f2 = ap[2], f3 = ap[3];
      float4 f4 = ap[4], f5 = ap[5], f6 = ap[6], f7 = ap[7];
      uint4 q0 = {pk2(f0.x, f0.y), pk2(f0.z, f0.w), pk2(f1.x, f1.y), pk2(f1.z, f1.w)};
      uint4 q1 = {pk2(f2.x, f2.y), pk2(f2.z, f2.w), pk2(f3.x, f3.y), pk2(f3.z, f3.w)};
      uint4 q2 = {pk2(f4.x, f4.y), pk2(f4.z, f4.w), pk2(f5.x, f5.y), pk2(f5.z, f5.w)};
      uint4 q3 = {pk2(f6.x, f6.y), pk2(f6.z, f6.w), pk2(f7.x, f7.y), pk2(f7.z, f7.w)};
      *(uint4*)(a_base + (0 ^ axr) * 8) = q0;
      *(uint4*)(a_base + (1 ^ axr) * 8) = q1;
      *(uint4*)(a_base + (2 ^ axr) * 8) = q2;
      *(uint4*)(a_base + (3 ^ axr) * 8) = q3;
    }
    __syncthreads();

#pragma unroll
    for (int h = 0; h < 2; ++h) {
      bf16x8 af[4], bfr[4];
#pragma unroll
      for (int m = 0; m < 4; ++m)
        af[m] = *(const bf16x8*)&As[h][(wr * 64 + m * 16 + (l & 15)) * 32 + rd_off];
#pragma unroll
      for (int n = 0; n < 4; ++n)
        bfr[n] = *(const bf16x8*)&Bs[h][(wc * 64 + n * 16 + (l & 15)) * 32 + rd_off];
#pragma unroll
      for (int m = 0; m < 4; ++m)
#pragma unroll
        for (int n = 0; n < 4; ++n)
          acc[m][n] = __builtin_amdgcn_mfma_f32_16x16x32_bf16(af[m], bfr[n], acc[m][n], 0, 0, 0);
    }
  }

  int rbase = row0 + wr * 64;
  int cbase = col0 + wc * 64;
#pragma unroll
  for (int m = 0; m < 4; ++m)
#pragma unroll
    for (int n = 0; n < 4; ++n)
#pragma unroll
      for (int i = 0; i < 4; ++i) {
        int rr = rbase + m * 16 + (l >> 4) * 4 + i;
        int cc = cbase + n * 16 + (l & 15);
        qm[(size_t)rr * D_ + cc] = f2bf(acc[m][n][i]);
      }
}

// ---------------- k3: logits -> sigmoid -> * w -> row-sum -> x --------------
// BM=64, BN=256, BK=64 (two [rows][32] panels), 4 waves (1x4). Same swizzles.
__global__ __launch_bounds__(256) void k_attn(const ushort* __restrict__ qm,
                                              const ushort* __restrict__ candb,
                                              const float* __restrict__ wbuf,
                                              const int* __restrict__ ctx_mask,
                                              float* __restrict__ xbuf) {
  __shared__ __align__(16) ushort As[2][64 * 32 + 8];
  __shared__ __align__(16) ushort Bs[2][256 * 32 + 8];
  __shared__ float w_lds[256];
  __shared__ float xpart[4][64];
  int bid0 = blockIdx.x;                    // 0..1023
  int nb = (bid0 & 7) * 128 + (bid0 >> 3);  // bijective XCD-chunked remap
  int b = nb >> 2, lt = nb & 3;
  int row0 = lt * 64;
  int tid = threadIdx.x, w = tid >> 6, l = tid & 63;
  int rd_off  = (((l >> 4) ^ ((l >> 2) & 3)) * 8);
  int src_off = (((l & 3) ^ ((l >> 4) & 3)) * 8);
  w_lds[tid] = wbuf[(size_t)b * 256 + tid];

  f32x4 acc[4][4];
#pragma unroll
  for (int m = 0; m < 4; ++m)
#pragma unroll
    for (int n = 0; n < 4; ++n) acc[m][n] = (f32x4){0.f, 0.f, 0.f, 0.f};

  size_t arow = (size_t)b * 256 + row0;
  size_t brow = (size_t)b * 256;

  for (int kt = 0; kt < D_; kt += 64) {
    if (kt) __syncthreads();
    // A: 1 gload/wave/panel
#pragma unroll
    for (int h = 0; h < 2; ++h) {
      const ushort* gsrc = qm + (arow + w * 16 + (l >> 2)) * D_ + kt + h * 32 + src_off;
      gload16(gsrc, (char*)As[h] + w * 1024);
    }
    // B: 4 gloads/wave/panel
#pragma unroll
    for (int h = 0; h < 2; ++h)
#pragma unroll
      for (int g = 0; g < 4; ++g) {
        int grp = w * 4 + g;
        const ushort* gsrc = candb + (brow + grp * 16 + (l >> 2)) * D_ + kt + h * 32 + src_off;
        gload16(gsrc, (char*)Bs[h] + grp * 1024);
      }
    __syncthreads();

#pragma unroll
    for (int h = 0; h < 2; ++h) {
      bf16x8 af[4], bfr[4];
#pragma unroll
      for (int m = 0; m < 4; ++m)
        af[m] = *(const bf16x8*)&As[h][(m * 16 + (l & 15)) * 32 + rd_off];
#pragma unroll
      for (int n = 0; n < 4; ++n)
        bfr[n] = *(const bf16x8*)&Bs[h][(w * 64 + n * 16 + (l & 15)) * 32 + rd_off];
#pragma unroll
      for (int m = 0; m < 4; ++m)
#pragma unroll
        for (int n = 0; n < 4; ++n)
          acc[m][n] = __builtin_amdgcn_mfma_f32_16x16x32_bf16(af[m], bfr[n], acc[m][n], 0, 0, 0);
    }
  }

  float rs[4][4];
#pragma unroll
  for (int m = 0; m < 4; ++m)
#pragma unroll
    for (int i = 0; i < 4; ++i) rs[m][i] = 0.f;

#pragma unroll
  for (int n = 0; n < 4; ++n) {
    float wcol = w_lds[w * 64 + n * 16 + (l & 15)];
#pragma unroll
    for (int m = 0; m < 4; ++m)
#pragma unroll
      for (int i = 0; i < 4; ++i) {
        float p = 1.f / (1.f + __expf(-acc[m][n][i]));
        rs[m][i] += p * wcol;
      }
  }
#pragma unroll
  for (int m = 0; m < 4; ++m)
#pragma unroll
    for (int i = 0; i < 4; ++i) {
      float v = rs[m][i];
      v += __shfl_xor(v, 1, 64);
      v += __shfl_xor(v, 2, 64);
      v += __shfl_xor(v, 4, 64);
      v += __shfl_xor(v, 8, 64);
      rs[m][i] = v;
    }
  if ((l & 15) == 0) {
#pragma unroll
    for (int m = 0; m < 4; ++m)
#pragma unroll
      for (int i = 0; i < 4; ++i)
        xpart[w][m * 16 + (l >> 4) * 4 + i] = rs[m][i];
  }
  __syncthreads();
  if (tid < 64) {
    float xs = xpart[0][tid] + xpart[1][tid] + xpart[2][tid] + xpart[3][tid];
    int gm = ctx_mask[(size_t)b * 256 + row0 + tid];
    xbuf[(size_t)b * 256 + row0 + tid] = gm ? xs : 0.f;
  }
}

// ---------------- k4: y[b] = (x[b]^T W1 + b1) W2 + b2 ----------------------
__global__ __launch_bounds__(128) void k_mlp(const float* __restrict__ xbuf,
                                             const float* __restrict__ W1,
                                             const float* __restrict__ b1,
                                             const float* __restrict__ W2,
                                             const float* __restrict__ b2,
                                             float* __restrict__ out) {
  int b = blockIdx.x, t = threadIdx.x;
  __shared__ float xl[256];
  __shared__ float hl[128];
  xl[t]       = xbuf[(size_t)b * 256 + t];
  xl[t + 128] = xbuf[(size_t)b * 256 + 128 + t];
  __syncthreads();
  float acc = b1[t];
#pragma unroll 8
  for (int ll = 0; ll < 256; ++ll) acc += xl[ll] * W1[ll * H_ + t];
  hl[t] = acc;
  __syncthreads();
  if (t < 5) {
    float y = b2[t];
#pragma unroll 8
    for (int h = 0; h < H_; ++h) y += hl[h] * W2[h * 5 + t];
    out[(size_t)b * 5 + t] = y;
  }
}

extern "C" void kernel_launch(void* const* d_in, const int* in_sizes, int n_in,
                              void* d_out, int out_size, void* d_ws, size_t ws_size,
                              hipStream_t stream) {
  const float* ctx       = (const float*)d_in[0];
  const float* cand      = (const float*)d_in[1];
  const int*   ctx_mask  = (const int*)d_in[2];
  const int*   cand_mask = (const int*)d_in[3];
  const float* WK        = (const float*)d_in[4];
  const float* WQ        = (const float*)d_in[5];
  const float* WV        = (const float*)d_in[6];
  const float* W1        = (const float*)d_in[7];
  const float* b1        = (const float*)d_in[8];
  const float* W2        = (const float*)d_in[9];
  const float* b2        = (const float*)d_in[10];
  float* out = (float*)d_out;

  char* ws = (char*)d_ws;
  size_t off = 0;
  auto alloc = [&](size_t bytes) {
    void* p = ws + off;
    off += (bytes + 255) & ~(size_t)255;
    return p;
  };
  ushort* Mt    = (ushort*)alloc((size_t)D_ * D_ * 2);            // 1.18 MB
  float*  wbuf  = (float*) alloc((size_t)B_ * SP_ * 4);           // 256 KB
  float*  xbuf  = (float*) alloc((size_t)B_ * L_ * 4);            // 256 KB
  ushort* candb = (ushort*)alloc((size_t)B_ * SP_ * D_ * 2);      // 100.7 MB
  ushort* qm    = (ushort*)alloc((size_t)B_ * L_ * D_ * 2);       // 100.7 MB
  (void)ws_size; (void)in_sizes; (void)n_in; (void)out_size;

  k_mt  <<<(D_ / 4) * 3,      256, 0, stream>>>(WK, WQ, Mt);
  k_cand<<<(B_ * SP_) / 4,    256, 0, stream>>>(cand, cand_mask, WV, candb, wbuf);
  k_qm  <<<B_ * L_ / 128 * 6, 256, 0, stream>>>(ctx, Mt, qm);
  k_attn<<<B_ * 4,            256, 0, stream>>>(qm, candb, wbuf, ctx_mask, xbuf);
  k_mlp <<<B_,                128, 0, stream>>>(xbuf, W1, b1, W2, b2, out);
}

// Round 5
// 366.351 us; speedup vs baseline: 1.1000x; 1.1000x over previous
//
#include <hip/hip_runtime.h>
#include <hip/hip_bf16.h>
#include <stdint.h>

#define B_  256
#define L_  256
#define S_  253
#define SP_ 256   // padded S
#define D_  768
#define H_  128

typedef __bf16 bf16x8 __attribute__((ext_vector_type(8)));
typedef float  f32x4  __attribute__((ext_vector_type(4)));

__device__ __forceinline__ ushort f2bf(float f) {
  union { float f; uint32_t u; } v; v.f = f;
  uint32_t r = v.u + 0x7FFFu + ((v.u >> 16) & 1u);  // RNE
  return (ushort)(r >> 16);
}

__device__ __forceinline__ void gload16(const void* g, void* l) {
  __builtin_amdgcn_global_load_lds((const __attribute__((address_space(1))) void*)g,
                                   (__attribute__((address_space(3))) void*)l,
                                   16, 0, 0);
}

// Swizzle derivation (LDS rows of 32 ushort = 64 B = 4 slots of 16 B):
//   stored slot s at row r holds global slot s ^ ((r>>1)&3).
//   gload writer: lane l = (row l>>2, slot l&3) within a 16-row group ->
//     global col offset ((l&3)^((l>>3)&3))*8 ushorts.
//   frag reader: row = .. + (l&15), wants global slot l>>4 ->
//     storage slot (l>>4)^((l>>1)&3).
//   Result: each 16-lane quarter of ds_read_b128 hits every bank exactly 2x.
#define SRC_OFF(l) ((((l) & 3) ^ (((l) >> 3) & 3)) * 8)
#define RD_OFF(l)  (((((l) >> 4) ^ (((l) >> 1) & 3))) * 8)

// ---------------- k0: Mt[i][j] = scale * sum_t WK[i,t] * WQ[j,t] (bf16) -----
__global__ __launch_bounds__(256) void k_mt(const float* __restrict__ WK,
                                            const float* __restrict__ WQ,
                                            ushort* __restrict__ Mt) {
  const float scale = 0.03608439182435161f;  // 1/sqrt(768)
  int bid = blockIdx.x;
  int i0 = (bid / 3) * 4;
  int j  = (bid % 3) * 256 + threadIdx.x;
  const float4* wq  = (const float4*)(WQ + (size_t)j * D_);
  const float4* wk0 = (const float4*)(WK + (size_t)(i0 + 0) * D_);
  const float4* wk1 = (const float4*)(WK + (size_t)(i0 + 1) * D_);
  const float4* wk2 = (const float4*)(WK + (size_t)(i0 + 2) * D_);
  const float4* wk3 = (const float4*)(WK + (size_t)(i0 + 3) * D_);
  float a0 = 0.f, a1 = 0.f, a2 = 0.f, a3 = 0.f;
#pragma unroll 4
  for (int t = 0; t < D_ / 4; ++t) {
    float4 q = wq[t];
    float4 k0 = wk0[t], k1 = wk1[t], k2 = wk2[t], k3 = wk3[t];
    a0 += q.x * k0.x + q.y * k0.y + q.z * k0.z + q.w * k0.w;
    a1 += q.x * k1.x + q.y * k1.y + q.z * k1.z + q.w * k1.w;
    a2 += q.x * k2.x + q.y * k2.y + q.z * k2.z + q.w * k2.w;
    a3 += q.x * k3.x + q.y * k3.y + q.z * k3.z + q.w * k3.w;
  }
  Mt[(size_t)(i0 + 0) * D_ + j] = f2bf(a0 * scale);
  Mt[(size_t)(i0 + 1) * D_ + j] = f2bf(a1 * scale);
  Mt[(size_t)(i0 + 2) * D_ + j] = f2bf(a2 * scale);
  Mt[(size_t)(i0 + 3) * D_ + j] = f2bf(a3 * scale);
}

// ---------------- k1: ctx f32 -> bf16, streaming ---------------------------
__global__ __launch_bounds__(256) void k_ctxb(const float* __restrict__ ctx,
                                              ushort* __restrict__ ctxb) {
  const int64_t n4 = (int64_t)B_ * L_ * D_ / 4;
  int64_t stride = (int64_t)gridDim.x * 256;
  for (int64_t i = (int64_t)blockIdx.x * 256 + threadIdx.x; i < n4; i += stride) {
    float4 c = ((const float4*)ctx)[i];
    ushort4 o;
    o.x = f2bf(c.x); o.y = f2bf(c.y); o.z = f2bf(c.z); o.w = f2bf(c.w);
    ((ushort4*)ctxb)[i] = o;
  }
}

// ---------------- k2: cand -> bf16 (padded), w[b,s] = mask * (cand . WV) ----
__global__ __launch_bounds__(256) void k_cand(const float* __restrict__ cand,
                                              const int* __restrict__ cand_mask,
                                              const float* __restrict__ WV,
                                              ushort* __restrict__ candb,
                                              float* __restrict__ wbuf) {
  int r = blockIdx.x * 4 + (threadIdx.x >> 6);  // padded row id, one wave per row
  int l = threadIdx.x & 63;
  int b = r >> 8, s = r & 255;
  float acc = 0.f;
  ushort* dst = candb + (size_t)r * D_;
  if (s < S_) {
    const float4* src = (const float4*)(cand + ((size_t)b * S_ + s) * D_);
    const float4* wv4 = (const float4*)WV;
#pragma unroll
    for (int i = 0; i < 3; ++i) {
      int d4 = i * 64 + l;
      float4 c = src[d4];
      float4 v = wv4[d4];
      acc += c.x * v.x + c.y * v.y + c.z * v.z + c.w * v.w;
      ushort4 o;
      o.x = f2bf(c.x); o.y = f2bf(c.y); o.z = f2bf(c.z); o.w = f2bf(c.w);
      *(ushort4*)(dst + d4 * 4) = o;
    }
  } else {
    ushort4 z = {0, 0, 0, 0};
#pragma unroll
    for (int i = 0; i < 3; ++i) *(ushort4*)(dst + (i * 64 + l) * 4) = z;
  }
#pragma unroll
  for (int off = 32; off > 0; off >>= 1) acc += __shfl_down(acc, off, 64);
  if (l == 0) {
    float wv = 0.f;
    if (s < S_ && cand_mask[(size_t)b * S_ + s] != 0) wv = acc;
    wbuf[r] = wv;
  }
}

// ---------------- k3: qm[r][c] = sum_k ctxb[r][k] * Mt[c][k]  (bf16 out) ----
// R3 structure (gload_lds both operands) + BK=64 (two 32-col panels, half the
// barriers) + bank-swizzle. 128x128 tile, 4 waves (2x2).
__global__ __launch_bounds__(256) void k_qm(const ushort* __restrict__ ctxb,
                                            const ushort* __restrict__ Mt,
                                            ushort* __restrict__ qm) {
  __shared__ __align__(16) ushort As[2][128 * 32];
  __shared__ __align__(16) ushort Bs[2][128 * 32];
  int bid0 = blockIdx.x;              // 0..3071
  int xcd = bid0 & 7;
  int idx = bid0 >> 3;                // 0..383
  int bm = xcd * 64 + idx / 6;        // 0..511 (bijective)
  int bn = idx % 6;
  int row0 = bm * 128, col0 = bn * 128;
  int tid = threadIdx.x;
  int w = tid >> 6, l = tid & 63;
  int wr = w >> 1, wc = w & 1;
  int src_off = SRC_OFF(l);
  int rd_off  = RD_OFF(l);

  f32x4 acc[4][4];
#pragma unroll
  for (int m = 0; m < 4; ++m)
#pragma unroll
    for (int n = 0; n < 4; ++n) acc[m][n] = (f32x4){0.f, 0.f, 0.f, 0.f};

  for (int kt = 0; kt < D_; kt += 64) {
    if (kt) __syncthreads();
#pragma unroll
    for (int h = 0; h < 2; ++h)
#pragma unroll
      for (int g = 0; g < 2; ++g) {
        int grp = w * 2 + g;
        int grow = grp * 16 + (l >> 2);
        const ushort* asrc = ctxb + (size_t)(row0 + grow) * D_ + kt + h * 32 + src_off;
        gload16(asrc, (char*)As[h] + grp * 1024);
        const ushort* bsrc = Mt + (size_t)(col0 + grow) * D_ + kt + h * 32 + src_off;
        gload16(bsrc, (char*)Bs[h] + grp * 1024);
      }
    __syncthreads();

#pragma unroll
    for (int h = 0; h < 2; ++h) {
      bf16x8 af[4], bfr[4];
#pragma unroll
      for (int m = 0; m < 4; ++m)
        af[m] = *(const bf16x8*)&As[h][(wr * 64 + m * 16 + (l & 15)) * 32 + rd_off];
#pragma unroll
      for (int n = 0; n < 4; ++n)
        bfr[n] = *(const bf16x8*)&Bs[h][(wc * 64 + n * 16 + (l & 15)) * 32 + rd_off];
#pragma unroll
      for (int m = 0; m < 4; ++m)
#pragma unroll
        for (int n = 0; n < 4; ++n)
          acc[m][n] = __builtin_amdgcn_mfma_f32_16x16x32_bf16(af[m], bfr[n], acc[m][n], 0, 0, 0);
    }
  }

  int rbase = row0 + wr * 64;
  int cbase = col0 + wc * 64;
#pragma unroll
  for (int m = 0; m < 4; ++m)
#pragma unroll
    for (int n = 0; n < 4; ++n)
#pragma unroll
      for (int i = 0; i < 4; ++i) {
        int rr = rbase + m * 16 + (l >> 4) * 4 + i;
        int cc = cbase + n * 16 + (l & 15);
        qm[(size_t)rr * D_ + cc] = f2bf(acc[m][n][i]);
      }
}

// ---------------- k4: logits -> sigmoid -> * w -> row-sum -> x --------------
// BM=64, BN=256, BK=64 (two panels), 4 waves (1x4), same swizzle.
__global__ __launch_bounds__(256) void k_attn(const ushort* __restrict__ qm,
                                              const ushort* __restrict__ candb,
                                              const float* __restrict__ wbuf,
                                              const int* __restrict__ ctx_mask,
                                              float* __restrict__ xbuf) {
  __shared__ __align__(16) ushort As[2][64 * 32];
  __shared__ __align__(16) ushort Bs[2][256 * 32];
  __shared__ float w_lds[256];
  __shared__ float xpart[4][64];
  int bid0 = blockIdx.x;                    // 0..1023
  int nb = (bid0 & 7) * 128 + (bid0 >> 3);  // bijective XCD-chunked remap
  int b = nb >> 2, lt = nb & 3;
  int row0 = lt * 64;
  int tid = threadIdx.x, w = tid >> 6, l = tid & 63;
  int src_off = SRC_OFF(l);
  int rd_off  = RD_OFF(l);
  w_lds[tid] = wbuf[(size_t)b * 256 + tid];

  f32x4 acc[4][4];
#pragma unroll
  for (int m = 0; m < 4; ++m)
#pragma unroll
    for (int n = 0; n < 4; ++n) acc[m][n] = (f32x4){0.f, 0.f, 0.f, 0.f};

  size_t arow = (size_t)b * 256 + row0;
  size_t brow = (size_t)b * 256;

  for (int kt = 0; kt < D_; kt += 64) {
    if (kt) __syncthreads();
    // A: 1 gload/wave/panel (16 rows each)
#pragma unroll
    for (int h = 0; h < 2; ++h) {
      const ushort* gsrc = qm + (arow + w * 16 + (l >> 2)) * D_ + kt + h * 32 + src_off;
      gload16(gsrc, (char*)As[h] + w * 1024);
    }
    // B: 4 gloads/wave/panel
#pragma unroll
    for (int h = 0; h < 2; ++h)
#pragma unroll
      for (int g = 0; g < 4; ++g) {
        int grp = w * 4 + g;
        const ushort* gsrc = candb + (brow + grp * 16 + (l >> 2)) * D_ + kt + h * 32 + src_off;
        gload16(gsrc, (char*)Bs[h] + grp * 1024);
      }
    __syncthreads();

#pragma unroll
    for (int h = 0; h < 2; ++h) {
      bf16x8 af[4], bfr[4];
#pragma unroll
      for (int m = 0; m < 4; ++m)
        af[m] = *(const bf16x8*)&As[h][(m * 16 + (l & 15)) * 32 + rd_off];
#pragma unroll
      for (int n = 0; n < 4; ++n)
        bfr[n] = *(const bf16x8*)&Bs[h][(w * 64 + n * 16 + (l & 15)) * 32 + rd_off];
#pragma unroll
      for (int m = 0; m < 4; ++m)
#pragma unroll
        for (int n = 0; n < 4; ++n)
          acc[m][n] = __builtin_amdgcn_mfma_f32_16x16x32_bf16(af[m], bfr[n], acc[m][n], 0, 0, 0);
    }
  }

  float rs[4][4];
#pragma unroll
  for (int m = 0; m < 4; ++m)
#pragma unroll
    for (int i = 0; i < 4; ++i) rs[m][i] = 0.f;

#pragma unroll
  for (int n = 0; n < 4; ++n) {
    float wcol = w_lds[w * 64 + n * 16 + (l & 15)];
#pragma unroll
    for (int m = 0; m < 4; ++m)
#pragma unroll
      for (int i = 0; i < 4; ++i) {
        float p = 1.f / (1.f + __expf(-acc[m][n][i]));
        rs[m][i] += p * wcol;
      }
  }
#pragma unroll
  for (int m = 0; m < 4; ++m)
#pragma unroll
    for (int i = 0; i < 4; ++i) {
      float v = rs[m][i];
      v += __shfl_xor(v, 1, 64);
      v += __shfl_xor(v, 2, 64);
      v += __shfl_xor(v, 4, 64);
      v += __shfl_xor(v, 8, 64);
      rs[m][i] = v;
    }
  if ((l & 15) == 0) {
#pragma unroll
    for (int m = 0; m < 4; ++m)
#pragma unroll
      for (int i = 0; i < 4; ++i)
        xpart[w][m * 16 + (l >> 4) * 4 + i] = rs[m][i];
  }
  __syncthreads();
  if (tid < 64) {
    float xs = xpart[0][tid] + xpart[1][tid] + xpart[2][tid] + xpart[3][tid];
    int gm = ctx_mask[(size_t)b * 256 + row0 + tid];
    xbuf[(size_t)b * 256 + row0 + tid] = gm ? xs : 0.f;
  }
}

// ---------------- k5: y[b] = (x[b]^T W1 + b1) W2 + b2 ----------------------
__global__ __launch_bounds__(128) void k_mlp(const float* __restrict__ xbuf,
                                             const float* __restrict__ W1,
                                             const float* __restrict__ b1,
                                             const float* __restrict__ W2,
                                             const float* __restrict__ b2,
                                             float* __restrict__ out) {
  int b = blockIdx.x, t = threadIdx.x;
  __shared__ float xl[256];
  __shared__ float hl[128];
  xl[t]       = xbuf[(size_t)b * 256 + t];
  xl[t + 128] = xbuf[(size_t)b * 256 + 128 + t];
  __syncthreads();
  float acc = b1[t];
#pragma unroll 8
  for (int ll = 0; ll < 256; ++ll) acc += xl[ll] * W1[ll * H_ + t];
  hl[t] = acc;
  __syncthreads();
  if (t < 5) {
    float y = b2[t];
#pragma unroll 8
    for (int h = 0; h < H_; ++h) y += hl[h] * W2[h * 5 + t];
    out[(size_t)b * 5 + t] = y;
  }
}

extern "C" void kernel_launch(void* const* d_in, const int* in_sizes, int n_in,
                              void* d_out, int out_size, void* d_ws, size_t ws_size,
                              hipStream_t stream) {
  const float* ctx       = (const float*)d_in[0];
  const float* cand      = (const float*)d_in[1];
  const int*   ctx_mask  = (const int*)d_in[2];
  const int*   cand_mask = (const int*)d_in[3];
  const float* WK        = (const float*)d_in[4];
  const float* WQ        = (const float*)d_in[5];
  const float* WV        = (const float*)d_in[6];
  const float* W1        = (const float*)d_in[7];
  const float* b1        = (const float*)d_in[8];
  const float* W2        = (const float*)d_in[9];
  const float* b2        = (const float*)d_in[10];
  float* out = (float*)d_out;

  char* ws = (char*)d_ws;
  size_t off = 0;
  auto alloc = [&](size_t bytes) {
    void* p = ws + off;
    off += (bytes + 255) & ~(size_t)255;
    return p;
  };
  ushort* Mt    = (ushort*)alloc((size_t)D_ * D_ * 2);            // 1.18 MB
  float*  wbuf  = (float*) alloc((size_t)B_ * SP_ * 4);           // 256 KB
  float*  xbuf  = (float*) alloc((size_t)B_ * L_ * 4);            // 256 KB
  ushort* candb = (ushort*)alloc((size_t)B_ * SP_ * D_ * 2);      // 100.7 MB
  ushort* qm    = (ushort*)alloc((size_t)B_ * L_ * D_ * 2);       // 100.7 MB
  ushort* ctxb  = (ushort*)alloc((size_t)B_ * L_ * D_ * 2);       // 100.7 MB
  (void)ws_size; (void)in_sizes; (void)n_in; (void)out_size;

  k_mt  <<<(D_ / 4) * 3,      256, 0, stream>>>(WK, WQ, Mt);
  k_ctxb<<<2048,              256, 0, stream>>>(ctx, ctxb);
  k_cand<<<(B_ * SP_) / 4,    256, 0, stream>>>(cand, cand_mask, WV, candb, wbuf);
  k_qm  <<<B_ * L_ / 128 * 6, 256, 0, stream>>>(ctxb, Mt, qm);
  k_attn<<<B_ * 4,            256, 0, stream>>>(qm, candb, wbuf, ctx_mask, xbuf);
  k_mlp <<<B_,                128, 0, stream>>>(xbuf, W1, b1, W2, b2, out);
}